// Round 4
// baseline (12.119 us; speedup 1.0000x reference)
//
#include <hip/hip_runtime.h>
#include <math.h>

#define NSYS_ 256

// f64 reciprocal: v_rcp_f64 + 2 Newton iterations (full f64 accuracy,
// ~4 ops vs ~10-op exact-div sequence).
__device__ __forceinline__ double frcp(double x) {
    double r = __builtin_amdgcn_rcp(x);
    double e = fma(-x, r, 1.0);
    r = fma(r, e, r);
    e = fma(-x, r, 1.0);
    r = fma(r, e, r);
    return r;
}

// Symmetric 3x3 inverse (adjugate). Reads lower triangle {0,3,4,6,7,8};
// writes all 9 (upper entries are register aliases, zero cost).
__device__ __forceinline__ void sym_inv3(const double D[9], double Dinv[9]) {
    const double a = D[0], b = D[3], c = D[4], d = D[6], e = D[7], f = D[8];
    const double A00 = c*f - e*e;
    const double A01 = d*e - b*f;
    const double A02 = b*e - c*d;
    const double A11 = a*f - d*d;
    const double A12 = b*d - a*e;
    const double A22 = a*c - b*b;
    const double det  = a*A00 + b*A01 + d*A02;
    const double idet = frcp(det);
    Dinv[0] = A00*idet; Dinv[1] = A01*idet; Dinv[2] = A02*idet;
    Dinv[3] = Dinv[1];  Dinv[4] = A11*idet; Dinv[5] = A12*idet;
    Dinv[6] = Dinv[2];  Dinv[7] = Dinv[5];  Dinv[8] = A22*idet;
}

// Interface rows for step h (verified rounds 1-3).
__device__ __forceinline__ void iface_rows(double h, double wL[5][3], double wR[5][3]) {
    const double ih = frcp(h);
    const double s1 = ih * ih;    // h^-2
    const double s0 = s1 * ih;    // h^-3
    const double hh = 0.5 * ih;   // 0.5*h^-1
    wL[0][0]= s0; wL[0][1]= s1; wL[0][2]= hh;  wR[0][0]=-s0; wR[0][1]=0.0; wR[0][2]=0.0;
    wL[1][0]=-s0; wL[1][1]=0.0; wL[1][2]=0.0;  wR[1][0]= s0; wR[1][1]=-s1; wR[1][2]= hh;
    wL[2][0]=0.0; wL[2][1]= s1; wL[2][2]= ih;  wR[2][0]=0.0; wR[2][1]=-s1; wR[2][2]=0.0;
    wL[3][0]=0.0; wL[3][1]=-s1; wL[3][2]=0.0;  wR[3][0]=0.0; wR[3][1]= s1; wR[3][2]=-ih;
    wL[4][0]=0.0; wL[4][1]=0.0; wL[4][2]=-ih;  wR[4][0]=0.0; wR[4][1]=0.0; wR[4][2]= ih;
}

// One wave per system; lane l owns rows 2l, 2l+1. Odd rows eliminated locally
// (exchange via shfl_up), then 6-stage PCR over 64 even rows with one barrier
// per stage, symmetric-only D arithmetic throughout. All f64.
__global__ __launch_bounds__(64)
void ode_pcr_1wave(const float* __restrict__ coeffs,
                   const float* __restrict__ rhs,
                   const float* __restrict__ ivr,
                   const float* __restrict__ steps,
                   float* __restrict__ out)
{
    const int sys = blockIdx.x;
    const int l   = threadIdx.x;           // 0..63
    const int m0  = 2*l, m1 = 2*l+1;

    const float* cP  = coeffs + (size_t)sys * 384;
    const float* rP  = rhs    + (size_t)sys * 128;
    const float* ivP = ivr    + (size_t)sys * 2;
    const float* hP  = steps  + (size_t)sys * 127;

    __shared__ double ex[2][18][64];

    const float hf0 = hP[m0];
    const float hf1 = (l < 63) ? hP[m1] : 0.0f;

    // ---- aux outputs first: store latency hides under the solve ------------
    {
        float* outH = out + 98305 + (size_t)sys*127;
        outH[m0] = hf0;
        if (l < 63) outH[m1] = hf1;
        if (sys == 0 && l == 0) out[98304] = 0.0f;
    }

    // ---------------- assembly (lower-triangle-only D0/D1) ------------------
    double D0[9], U0[9], r0[3], D1[9], U1[9], r1[3];
    {
        const double c0[3] = {(double)cP[m0*3+0], (double)cP[m0*3+1], (double)cP[m0*3+2]};
        const double c1[3] = {(double)cP[m1*3+0], (double)cP[m1*3+1], (double)cP[m1*3+2]};
        const double rv0 = (double)rP[m0], rv1 = (double)rP[m1];
        #pragma unroll
        for (int a=0;a<3;++a){
          #pragma unroll
          for (int b=0;b<=a;++b){ D0[a*3+b]=c0[a]*c0[b]; D1[a*3+b]=c1[a]*c1[b]; }
          #pragma unroll
          for (int b=0;b<3;++b){ U0[a*3+b]=0.0; U1[a*3+b]=0.0; }
          r0[a]=c0[a]*rv0; r1[a]=c1[a]*rv1;
        }
    }
    { // interface at h_{m0}: D0 (left), U0, D1 (right)
        double wL[5][3], wR[5][3];
        iface_rows((double)hf0, wL, wR);
        #pragma unroll
        for (int k=0;k<5;++k)
          #pragma unroll
          for (int a=0;a<3;++a){
            #pragma unroll
            for (int b=0;b<=a;++b){
              D0[a*3+b] += wL[k][a]*wL[k][b];
              D1[a*3+b] += wR[k][a]*wR[k][b];
            }
            #pragma unroll
            for (int b=0;b<3;++b)
              U0[a*3+b] += wL[k][a]*wR[k][b];
          }
    }
    if (l >= 1) { // interface at h_{m0-1}: D0 (right)
        double wL[5][3], wR[5][3];
        iface_rows((double)hP[m0-1], wL, wR);
        #pragma unroll
        for (int k=0;k<5;++k)
          #pragma unroll
          for (int a=0;a<3;++a)
            #pragma unroll
            for (int b=0;b<=a;++b)
              D0[a*3+b] += wR[k][a]*wR[k][b];
    }
    if (l < 63) { // interface at h_{m1}: D1 (left), U1
        double wL[5][3], wR[5][3];
        iface_rows((double)hf1, wL, wR);
        #pragma unroll
        for (int k=0;k<5;++k)
          #pragma unroll
          for (int a=0;a<3;++a){
            #pragma unroll
            for (int b=0;b<=a;++b)
              D1[a*3+b] += wL[k][a]*wL[k][b];
            #pragma unroll
            for (int b=0;b<3;++b)
              U1[a*3+b] += wL[k][a]*wR[k][b];
          }
    }
    if (l == 0) { // hard-constraint elimination x0=iv0, x1=iv1
        const double iv0 = (double)ivP[0], iv1 = (double)ivP[1];
        #pragma unroll
        for (int b=0;b<3;++b) r1[b] -= U0[0*3+b]*iv0 + U0[1*3+b]*iv1;  // ORIGINAL U0
        #pragma unroll
        for (int b=0;b<3;++b){ U0[0*3+b]=0.0; U0[1*3+b]=0.0; }
        r0[2] -= D0[6]*iv0 + D0[7]*iv1;
        r0[0] = iv0; r0[1] = iv1;
        D0[3]=0.0; D0[6]=0.0; D0[7]=0.0;
        D0[0]=1.0; D0[4]=1.0;
    }

    // ---------------- eliminate odd row m1 (local CR level) ------------------
    double TA[9], TB[9], z1[3];
    {
        double Dinv1[9]; sym_inv3(D1, Dinv1);
        #pragma unroll
        for (int a=0;a<3;++a)
          #pragma unroll
          for (int k=0;k<3;++k){
            TA[a*3+k] = U0[a*3+0]*Dinv1[0*3+k] + U0[a*3+1]*Dinv1[1*3+k] + U0[a*3+2]*Dinv1[2*3+k];
            TB[a*3+k] = Dinv1[a*3+0]*U1[0*3+k] + Dinv1[a*3+1]*U1[1*3+k] + Dinv1[a*3+2]*U1[2*3+k];
          }
        #pragma unroll
        for (int j=0;j<3;++j)
          z1[j] = Dinv1[j*3+0]*r1[0] + Dinv1[j*3+1]*r1[1] + Dinv1[j*3+2]*r1[2];
    }
    double D[9], U[9], r[3];
    #pragma unroll
    for (int a=0;a<3;++a){
      #pragma unroll
      for (int b=0;b<=a;++b)
        D[a*3+b] = D0[a*3+b] - (TA[a*3+0]*U0[b*3+0] + TA[a*3+1]*U0[b*3+1] + TA[a*3+2]*U0[b*3+2]);
      #pragma unroll
      for (int b=0;b<3;++b)
        U[a*3+b] = -(TA[a*3+0]*U1[0*3+b] + TA[a*3+1]*U1[1*3+b] + TA[a*3+2]*U1[2*3+b]);
      r[a] = r0[a] - (TA[a*3+0]*r1[0] + TA[a*3+1]*r1[1] + TA[a*3+2]*r1[2]);
    }
    { // fill into next even row: Cn = U1^T Dinv1 U1 (lower6), cn = U1^T z1; shfl_up
        double q[9];
        q[0] = U1[0]*TB[0] + U1[3]*TB[3] + U1[6]*TB[6];
        q[1] = U1[1]*TB[0] + U1[4]*TB[3] + U1[7]*TB[6];
        q[2] = U1[2]*TB[0] + U1[5]*TB[3] + U1[8]*TB[6];
        q[3] = U1[1]*TB[1] + U1[4]*TB[4] + U1[7]*TB[7];
        q[4] = U1[2]*TB[1] + U1[5]*TB[4] + U1[8]*TB[7];
        q[5] = U1[2]*TB[2] + U1[5]*TB[5] + U1[8]*TB[8];
        q[6] = U1[0]*z1[0] + U1[3]*z1[1] + U1[6]*z1[2];
        q[7] = U1[1]*z1[0] + U1[4]*z1[1] + U1[7]*z1[2];
        q[8] = U1[2]*z1[0] + U1[5]*z1[1] + U1[8]*z1[2];
        double qi[9];
        #pragma unroll
        for (int i=0;i<9;++i) qi[i] = __shfl_up(q[i], 1);
        if (l >= 1) {
            D[0]-=qi[0]; D[3]-=qi[1]; D[6]-=qi[2]; D[4]-=qi[3]; D[7]-=qi[4]; D[8]-=qi[5];
            r[0]-=qi[6]; r[1]-=qi[7]; r[2]-=qi[8];
        }
    }

    // ---------------- PCR over 64 even rows: 6 stages, 1 barrier each --------
    #pragma unroll 1
    for (int s = 0; s < 6; ++s) {
        const int d = 1 << s;
        double Dinv[9]; sym_inv3(D, Dinv);
        double (*buf)[64] = ex[s & 1];
        buf[0][l]=Dinv[0]; buf[1][l]=Dinv[1]; buf[2][l]=Dinv[2];
        buf[3][l]=Dinv[4]; buf[4][l]=Dinv[5]; buf[5][l]=Dinv[8];
        #pragma unroll
        for (int i=0;i<9;++i) buf[6+i][l]=U[i];
        buf[15][l]=r[0]; buf[16][l]=r[1]; buf[17][l]=r[2];
        __syncthreads();

        // lower6 of new D in order {00,10,20,11,21,22}
        double nD[6] = { D[0], D[3], D[6], D[4], D[7], D[8] };
        double nU[9];
        #pragma unroll
        for (int i=0;i<9;++i) nU[i]=0.0;
        double nr[3] = { r[0], r[1], r[2] };

        if (l + d < 64) {
            const int p = l + d;
            double Dp[9];
            Dp[0]=buf[0][p]; Dp[1]=buf[1][p]; Dp[2]=buf[2][p];
            Dp[3]=Dp[1];     Dp[4]=buf[3][p]; Dp[5]=buf[4][p];
            Dp[6]=Dp[2];     Dp[7]=Dp[5];     Dp[8]=buf[5][p];
            const double rp0=buf[15][p], rp1=buf[16][p], rp2=buf[17][p];
            double T[9];
            #pragma unroll
            for (int a=0;a<3;++a)
              #pragma unroll
              for (int k=0;k<3;++k)
                T[a*3+k] = U[a*3+0]*Dp[0*3+k] + U[a*3+1]*Dp[1*3+k] + U[a*3+2]*Dp[2*3+k];
            nD[0] -= T[0]*U[0] + T[1]*U[1] + T[2]*U[2];
            nD[1] -= T[3]*U[0] + T[4]*U[1] + T[5]*U[2];
            nD[2] -= T[6]*U[0] + T[7]*U[1] + T[8]*U[2];
            nD[3] -= T[3]*U[3] + T[4]*U[4] + T[5]*U[5];
            nD[4] -= T[6]*U[3] + T[7]*U[4] + T[8]*U[5];
            nD[5] -= T[6]*U[6] + T[7]*U[7] + T[8]*U[8];
            nr[0] -= T[0]*rp0 + T[1]*rp1 + T[2]*rp2;
            nr[1] -= T[3]*rp0 + T[4]*rp1 + T[5]*rp2;
            nr[2] -= T[6]*rp0 + T[7]*rp1 + T[8]*rp2;
            if (s < 5) {   // last stage: nU never used
                double Up[9];
                #pragma unroll
                for (int i=0;i<9;++i) Up[i]=buf[6+i][p];
                #pragma unroll
                for (int a=0;a<3;++a)
                  #pragma unroll
                  for (int b=0;b<3;++b)
                    nU[a*3+b] = -(T[a*3+0]*Up[0*3+b] + T[a*3+1]*Up[1*3+b] + T[a*3+2]*Up[2*3+b]);
            }
        }
        if (l >= d) {
            const int p = l - d;
            double Dm[9];
            Dm[0]=buf[0][p]; Dm[1]=buf[1][p]; Dm[2]=buf[2][p];
            Dm[3]=Dm[1];     Dm[4]=buf[3][p]; Dm[5]=buf[4][p];
            Dm[6]=Dm[2];     Dm[7]=Dm[5];     Dm[8]=buf[5][p];
            double Um[9];
            #pragma unroll
            for (int i=0;i<9;++i) Um[i]=buf[6+i][p];
            const double rm0=buf[15][p], rm1=buf[16][p], rm2=buf[17][p];
            double Tm[9];
            #pragma unroll
            for (int a=0;a<3;++a)
              #pragma unroll
              for (int k=0;k<3;++k)
                Tm[a*3+k] = Um[0*3+a]*Dm[0*3+k] + Um[1*3+a]*Dm[1*3+k] + Um[2*3+a]*Dm[2*3+k];
            nD[0] -= Tm[0]*Um[0] + Tm[1]*Um[3] + Tm[2]*Um[6];
            nD[1] -= Tm[3]*Um[0] + Tm[4]*Um[3] + Tm[5]*Um[6];
            nD[2] -= Tm[6]*Um[0] + Tm[7]*Um[3] + Tm[8]*Um[6];
            nD[3] -= Tm[3]*Um[1] + Tm[4]*Um[4] + Tm[5]*Um[7];
            nD[4] -= Tm[6]*Um[1] + Tm[7]*Um[4] + Tm[8]*Um[7];
            nD[5] -= Tm[6]*Um[2] + Tm[7]*Um[5] + Tm[8]*Um[8];
            nr[0] -= Tm[0]*rm0 + Tm[1]*rm1 + Tm[2]*rm2;
            nr[1] -= Tm[3]*rm0 + Tm[4]*rm1 + Tm[5]*rm2;
            nr[2] -= Tm[6]*rm0 + Tm[7]*rm1 + Tm[8]*rm2;
        }
        D[0]=nD[0]; D[3]=nD[1]; D[6]=nD[2]; D[4]=nD[3]; D[7]=nD[4]; D[8]=nD[5];
        if (s < 5) {
            #pragma unroll
            for (int i=0;i<9;++i) U[i]=nU[i];
        }
        r[0]=nr[0]; r[1]=nr[1]; r[2]=nr[2];
    }

    // ---------------- decoupled even solve + odd back-substitution ----------
    double Dinv[9]; sym_inv3(D, Dinv);
    const double xe0 = Dinv[0]*r[0] + Dinv[1]*r[1] + Dinv[2]*r[2];
    const double xe1 = Dinv[3]*r[0] + Dinv[4]*r[1] + Dinv[5]*r[2];
    const double xe2 = Dinv[6]*r[0] + Dinv[7]*r[1] + Dinv[8]*r[2];
    double xN0 = __shfl_down(xe0, 1);
    double xN1 = __shfl_down(xe1, 1);
    double xN2 = __shfl_down(xe2, 1);
    if (l == 63) { xN0 = 0.0; xN1 = 0.0; xN2 = 0.0; }
    double xo[3];
    #pragma unroll
    for (int j=0;j<3;++j)
        xo[j] = z1[j] - (TA[0*3+j]*xe0 + TA[1*3+j]*xe1 + TA[2*3+j]*xe2)
                      - (TB[j*3+0]*xN0 + TB[j*3+1]*xN1 + TB[j*3+2]*xN2);

    // ---------------- outputs ------------------------------------------------
    float2* o0 = (float2*)(out)         + (size_t)sys*64;
    float2* o1 = (float2*)(out + 32768) + (size_t)sys*64;
    float2* o2 = (float2*)(out + 65536) + (size_t)sys*64;
    o0[l] = make_float2((float)xe0, (float)xo[0]);
    o1[l] = make_float2((float)xe1, (float)xo[1]);
    o2[l] = make_float2((float)xe2, (float)xo[2]);
}

extern "C" void kernel_launch(void* const* d_in, const int* in_sizes, int n_in,
                              void* d_out, int out_size, void* d_ws, size_t ws_size,
                              hipStream_t stream) {
    const float* coeffs = (const float*)d_in[0];
    const float* rhs    = (const float*)d_in[1];
    const float* ivr    = (const float*)d_in[2];
    const float* steps  = (const float*)d_in[3];
    float* out = (float*)d_out;
    (void)in_sizes; (void)n_in; (void)out_size; (void)d_ws; (void)ws_size;
    hipLaunchKernelGGL(ode_pcr_1wave, dim3(NSYS_), dim3(64), 0, stream,
                       coeffs, rhs, ivr, steps, out);
}